// Round 5
// baseline (231.175 us; speedup 1.0000x reference)
//
#include <hip/hip_runtime.h>

#define N_PY 512
#define IN_F 6
#define OUT_F 64
#define N_CELLS (512 * 512)
#define N_BUCKETS 2048            // cell >> 7
#define N_SB (N_BUCKETS * 4)      // sub-bucket = (cell>>7)*4 | (cell&3)
#define BN_EPS 1e-5

// ---------------------------------------------------------------------------
// ws layout (binned path):
//   [0, 108)            : 27 floats — moment accumulators
//   [512, 2048)         : float Wp[64*6], float bp[64] — BN-folded params
//   [4096, +32KB)       : int hist[8192]    — per-sub-bucket point count
//   [36864, +32772)     : int S[8193]       — exclusive scan (S[8192]=n)
//   [69888, +32KB)      : int cursor[8192]  — mutable copy of scan for binning
//   [102656, +32*n)     : float rec[n*8]    — 32B records {x0..x5, cell, pad}
// fallback (linked-list) reuses [4096...) as head[N_CELLS] + nxt[n].
// ---------------------------------------------------------------------------

__global__ void __launch_bounds__(256)
pfn_stats_hist_kernel(const float* __restrict__ x, const int* __restrict__ idx,
                      int n, float* __restrict__ acc, int* __restrict__ hist) {
    const int tid = blockIdx.x * blockDim.x + threadIdx.x;
    const int stride = gridDim.x * blockDim.x;
    const int npairs = n >> 1;

    float s[27];
#pragma unroll
    for (int k = 0; k < 27; ++k) s[k] = 0.f;

    for (int q = tid; q < npairs; q += stride) {
        const float4* base4 = (const float4*)(x + (size_t)q * 12);
        const float4 a = base4[0];
        const float4 b4 = base4[1];
        const float4 c4 = base4[2];
        const float p0[6] = {a.x, a.y, a.z, a.w, b4.x, b4.y};
        const float p1[6] = {b4.z, b4.w, c4.x, c4.y, c4.z, c4.w};
#pragma unroll
        for (int j = 0; j < 6; ++j) s[j] += p0[j] + p1[j];
        int k = 6;
#pragma unroll
        for (int i = 0; i < 6; ++i)
#pragma unroll
            for (int j = i; j < 6; ++j) {
                s[k] += p0[i] * p0[j] + p1[i] * p1[j];
                ++k;
            }
    }
    if ((n & 1) && tid == 0) {
        const float* p = x + (size_t)(n - 1) * 6;
        float v[6];
#pragma unroll
        for (int j = 0; j < 6; ++j) v[j] = p[j];
#pragma unroll
        for (int j = 0; j < 6; ++j) s[j] += v[j];
        int k = 6;
#pragma unroll
        for (int i = 0; i < 6; ++i)
#pragma unroll
            for (int j = i; j < 6; ++j) { s[k] += v[i] * v[j]; ++k; }
    }

    // sub-bucket histogram: fire-and-forget int atomics on 32KB L2-resident array
    for (int p = tid; p < n; p += stride) {
        const int2 ij = ((const int2*)idx)[p];
        const int cell = ij.x * N_PY + ij.y;
        atomicAdd(&hist[((cell >> 7) << 2) | (cell & 3)], 1);
    }

#pragma unroll
    for (int off = 32; off > 0; off >>= 1)
#pragma unroll
        for (int k = 0; k < 27; ++k) s[k] += __shfl_down(s[k], off, 64);

    __shared__ float lds[4][27];
    const int wid = threadIdx.x >> 6;
    const int lane = threadIdx.x & 63;
    if (lane == 0)
#pragma unroll
        for (int k = 0; k < 27; ++k) lds[wid][k] = s[k];
    __syncthreads();

    if (threadIdx.x < 27) {
        const int k = threadIdx.x;
        const float v = lds[0][k] + lds[1][k] + lds[2][k] + lds[3][k];
        atomicAdd(&acc[k], v);
    }
}

// single block: exclusive scan of hist[8192] -> S[] and cursor[], then fold
// BN stats into linear params (threads 0..63).
__global__ void __launch_bounds__(256)
pfn_scan_finalize_kernel(const int* __restrict__ hist,
                         int* __restrict__ S, int* __restrict__ cursor, int n,
                         const float* __restrict__ acc,
                         const float* __restrict__ W,
                         const float* __restrict__ b,
                         const float* __restrict__ gamma,
                         const float* __restrict__ beta,
                         float* __restrict__ Wp, float* __restrict__ bp) {
    const int tid = threadIdx.x;   // 256 threads x 32 entries = 8192
    int v[32];
    const int4* h4 = (const int4*)(hist + tid * 32);
#pragma unroll
    for (int g = 0; g < 8; ++g) {
        const int4 q = h4[g];
        v[g * 4 + 0] = q.x; v[g * 4 + 1] = q.y;
        v[g * 4 + 2] = q.z; v[g * 4 + 3] = q.w;
    }
    int pre[32];
    int tot = 0;
#pragma unroll
    for (int k = 0; k < 32; ++k) { pre[k] = tot; tot += v[k]; }

    __shared__ int sc[256];
    sc[tid] = tot;
    __syncthreads();
#pragma unroll
    for (int off = 1; off < 256; off <<= 1) {
        const int add = (tid >= off) ? sc[tid - off] : 0;
        __syncthreads();
        sc[tid] += add;
        __syncthreads();
    }
    const int excl = sc[tid] - tot;
#pragma unroll
    for (int k = 0; k < 32; ++k) {
        const int val = excl + pre[k];
        S[tid * 32 + k] = val;
        cursor[tid * 32 + k] = val;
    }
    if (tid == 255) S[8192] = n;

    // ---- BN-fold (independent of scan data) ----
    if (tid < 64) {
        const int f = tid;
        double inv_n = 1.0 / (double)n;
        double mx[6];
#pragma unroll
        for (int j = 0; j < 6; ++j) mx[j] = (double)acc[j] * inv_n;
        double C[6][6];
        {
            int k = 0;
            for (int i = 0; i < 6; ++i)
                for (int j = i; j < 6; ++j) {
                    double e = (double)acc[6 + k] * inv_n - mx[i] * mx[j];
                    C[i][j] = e; C[j][i] = e; ++k;
                }
        }
        double w[6];
#pragma unroll
        for (int j = 0; j < 6; ++j) w[j] = (double)W[f * 6 + j];
        double mean_h = (double)b[f];
#pragma unroll
        for (int j = 0; j < 6; ++j) mean_h += w[j] * mx[j];
        double var_h = 0.0;
        for (int i = 0; i < 6; ++i) {
            double t = 0.0;
            for (int j = 0; j < 6; ++j) t += C[i][j] * w[j];
            var_h += w[i] * t;
        }
        double sgn = (double)gamma[f] / sqrt(var_h + BN_EPS);
#pragma unroll
        for (int j = 0; j < 6; ++j) Wp[f * 6 + j] = (float)(w[j] * sgn);
        bp[f] = (float)(((double)b[f] - mean_h) * sgn + (double)beta[f]);
    }
}

// bin points: 32B-aligned record {x0..x5, cell, 0} into sub-bucket region
__global__ void __launch_bounds__(256)
pfn_bin_kernel(const float* __restrict__ x, const int* __restrict__ idx,
               int* __restrict__ cursor, float* __restrict__ rec, int n) {
    const int p = blockIdx.x * blockDim.x + threadIdx.x;
    if (p >= n) return;
    const int2 ij = ((const int2*)idx)[p];
    const int cell = ij.x * N_PY + ij.y;
    const int sb = ((cell >> 7) << 2) | (cell & 3);
    const int pos = atomicAdd(&cursor[sb], 1);

    const float2* xp = (const float2*)(x + (size_t)p * 6);
    const float2 a = xp[0], b2 = xp[1], c = xp[2];
    float4* d = (float4*)(rec + (size_t)pos * 8);
    d[0] = float4{a.x, a.y, b2.x, b2.y};
    d[1] = float4{c.x, c.y, __int_as_float(cell), 0.f};
}

// one block per 128-cell bucket: accumulate into 32KB LDS tile, coalesced flush.
// wave w exclusively consumes sub-bucket (bucket*4+w)  ->  no races, no atomics.
__global__ void __launch_bounds__(256)
pfn_tile_kernel(const float* __restrict__ rec, const int* __restrict__ S,
                const float* __restrict__ Wp, const float* __restrict__ bp,
                float* __restrict__ out) {
    __shared__ float tile[128 * OUT_F];   // 32 KB
    const int tid = threadIdx.x;
    const int lane = tid & 63;
    const int wid = tid >> 6;
    const int bucket = blockIdx.x;

    float4* t4 = (float4*)tile;
#pragma unroll
    for (int i = 0; i < 8; ++i)
        t4[tid + 256 * i] = float4{0.f, 0.f, 0.f, 0.f};

    const float w0 = Wp[lane * 6 + 0];
    const float w1 = Wp[lane * 6 + 1];
    const float w2 = Wp[lane * 6 + 2];
    const float w3 = Wp[lane * 6 + 3];
    const float w4 = Wp[lane * 6 + 4];
    const float w5 = Wp[lane * 6 + 5];
    const float bb = bp[lane];

    __syncthreads();

    const int sb = (bucket << 2) | wid;
    const int r0 = S[sb];
    const int r1 = S[sb + 1];

    for (int r = r0; r < r1; ++r) {
        const float4* rp = (const float4*)(rec + (size_t)r * 8);
        const float4 A0 = rp[0];          // wave-uniform broadcast load
        const float4 A1 = rp[1];
        const int cell = __float_as_int(A1.z);
        float v = bb;
        v = fmaf(w0, A0.x, v);
        v = fmaf(w1, A0.y, v);
        v = fmaf(w2, A0.z, v);
        v = fmaf(w3, A0.w, v);
        v = fmaf(w4, A1.x, v);
        v = fmaf(w5, A1.y, v);
        v = fmaxf(v, 0.f);
        const int o = ((cell & 127) << 6) | lane;   // stride-1 across lanes
        tile[o] += v;
    }
    __syncthreads();

    float4* o4 = (float4*)(out + (size_t)bucket * (128 * OUT_F));
#pragma unroll
    for (int i = 0; i < 8; ++i)
        o4[tid + 256 * i] = t4[tid + 256 * i];
}

// ---- fallback (linked-list path, ~small ws) ----
__global__ void __launch_bounds__(256)
pfn_build_kernel(const int* __restrict__ idx, int n,
                 int* __restrict__ head, int* __restrict__ nxt) {
    const int p = blockIdx.x * blockDim.x + threadIdx.x;
    if (p >= n) return;
    const int2 ij = ((const int2*)idx)[p];
    const int cell = ij.x * N_PY + ij.y;
    nxt[p] = atomicExch(&head[cell], p);
}

__global__ void pfn_finalize_kernel(const float* __restrict__ acc,
                                    const float* __restrict__ W,
                                    const float* __restrict__ b,
                                    const float* __restrict__ gamma,
                                    const float* __restrict__ beta,
                                    int n,
                                    float* __restrict__ Wp,
                                    float* __restrict__ bp) {
    int f = threadIdx.x;
    double inv_n = 1.0 / (double)n;
    double mx[6];
#pragma unroll
    for (int j = 0; j < 6; ++j) mx[j] = (double)acc[j] * inv_n;
    double C[6][6];
    {
        int k = 0;
        for (int i = 0; i < 6; ++i)
            for (int j = i; j < 6; ++j) {
                double e = (double)acc[6 + k] * inv_n - mx[i] * mx[j];
                C[i][j] = e; C[j][i] = e; ++k;
            }
    }
    double w[6];
#pragma unroll
    for (int j = 0; j < 6; ++j) w[j] = (double)W[f * 6 + j];
    double mean_h = (double)b[f];
#pragma unroll
    for (int j = 0; j < 6; ++j) mean_h += w[j] * mx[j];
    double var_h = 0.0;
    for (int i = 0; i < 6; ++i) {
        double t = 0.0;
        for (int j = 0; j < 6; ++j) t += C[i][j] * w[j];
        var_h += w[i] * t;
    }
    double s = (double)gamma[f] / sqrt(var_h + BN_EPS);
#pragma unroll
    for (int j = 0; j < 6; ++j) Wp[f * 6 + j] = (float)(w[j] * s);
    bp[f] = (float)(((double)b[f] - mean_h) * s + (double)beta[f]);
}

__global__ void __launch_bounds__(256)
pfn_output_kernel(const float* __restrict__ x,
                  const int* __restrict__ head,
                  const int* __restrict__ nxt,
                  const float* __restrict__ Wp,
                  const float* __restrict__ bp,
                  float* __restrict__ out) {
    const int lane = threadIdx.x & 63;
    const int cell = __builtin_amdgcn_readfirstlane(
        (int)((blockIdx.x * blockDim.x + threadIdx.x) >> 6));

    const float w0 = Wp[lane * 6 + 0];
    const float w1 = Wp[lane * 6 + 1];
    const float w2 = Wp[lane * 6 + 2];
    const float w3 = Wp[lane * 6 + 3];
    const float w4 = Wp[lane * 6 + 4];
    const float w5 = Wp[lane * 6 + 5];
    const float bb = bp[lane];

    float s = 0.f;
    int p = head[cell];
    while (p >= 0) {
        const float* xp = x + (size_t)p * 6;
        const int pn = nxt[p];
        float v = bb;
        v = fmaf(w0, xp[0], v);
        v = fmaf(w1, xp[1], v);
        v = fmaf(w2, xp[2], v);
        v = fmaf(w3, xp[3], v);
        v = fmaf(w4, xp[4], v);
        v = fmaf(w5, xp[5], v);
        s += fmaxf(v, 0.0f);
        p = pn;
    }
    out[(size_t)cell * OUT_F + lane] = s;
}

extern "C" void kernel_launch(void* const* d_in, const int* in_sizes, int n_in,
                              void* d_out, int out_size, void* d_ws, size_t ws_size,
                              hipStream_t stream) {
    const float* x     = (const float*)d_in[0];
    const int*   idx   = (const int*)d_in[1];
    const float* W     = (const float*)d_in[2];
    const float* b     = (const float*)d_in[3];
    const float* gamma = (const float*)d_in[4];
    const float* beta  = (const float*)d_in[5];
    float* out = (float*)d_out;

    const int n = in_sizes[0] / IN_F;

    float* acc = (float*)d_ws;
    float* Wp  = (float*)((char*)d_ws + 512);
    float* bp  = Wp + OUT_F * IN_F;

    int*   hist   = (int*)((char*)d_ws + 4096);     // 8192 ints
    int*   S      = (int*)((char*)d_ws + 36864);    // 8193 ints
    int*   cursor = (int*)((char*)d_ws + 69888);    // 8192 ints
    float* rec    = (float*)((char*)d_ws + 102656); // n * 8 floats, 32B recs

    const size_t need = 102656 + (size_t)n * 32;

    if (ws_size >= need) {
        // zero acc + hist in one memset (S/cursor fully written by scan kernel)
        hipMemsetAsync(d_ws, 0, 36864, stream);
        pfn_stats_hist_kernel<<<512, 256, 0, stream>>>(x, idx, n, acc, hist);
        pfn_scan_finalize_kernel<<<1, 256, 0, stream>>>(
            hist, S, cursor, n, acc, W, b, gamma, beta, Wp, bp);
        pfn_bin_kernel<<<(n + 255) / 256, 256, 0, stream>>>(x, idx, cursor, rec, n);
        pfn_tile_kernel<<<N_BUCKETS, 256, 0, stream>>>(rec, S, Wp, bp, out);
    } else {
        // linked-list fallback
        int* head = (int*)((char*)d_ws + 4096);
        int* nxt  = head + N_CELLS;
        hipMemsetAsync(d_ws, 0, 512, stream);
        pfn_stats_hist_kernel<<<512, 256, 0, stream>>>(x, idx, n, acc, head);
        hipMemsetAsync(head, 0xFF, (size_t)N_CELLS * sizeof(int), stream);
        pfn_finalize_kernel<<<1, 64, 0, stream>>>(acc, W, b, gamma, beta, n, Wp, bp);
        pfn_build_kernel<<<(n + 255) / 256, 256, 0, stream>>>(idx, n, head, nxt);
        pfn_output_kernel<<<N_CELLS / 4, 256, 0, stream>>>(x, head, nxt, Wp, bp, out);
    }
}

// Round 6
// 201.171 us; speedup vs baseline: 1.1491x; 1.1491x over previous
//
#include <hip/hip_runtime.h>

#define N_PY 512
#define IN_F 6
#define OUT_F 64
#define N_CELLS (512 * 512)
#define N_BUCKETS 4096            // cell >> 6  (64 cells per bucket)
#define N_SB (N_BUCKETS * 4)      // sub-bucket = (cell>>6)*4 | (cell&3) = 16384
#define BN_EPS 1e-5

// ---------------------------------------------------------------------------
// ws layout (binned path):
//   [0, 108)         : 27 floats — moment accumulators
//   [512, 2048)      : float Wp[64*6], float bp[64] — BN-folded params
//   [4096, 69632)    : int hist[16384]   — per-sub-bucket point count
//   [69632, 135172)  : int S[16385]      — exclusive scan (S[16384]=n)
//   [135680, 201216) : int cursor[16384] — mutable copy of scan for binning
//   [201216, +32*n)  : float rec[n*8]    — 32B records {x0..x5, cell, pad}
// fallback (linked-list) reuses [4096...) as head[N_CELLS] + nxt[n].
// ---------------------------------------------------------------------------

__device__ __forceinline__ int sub_bucket(int cell) {
    return ((cell >> 6) << 2) | (cell & 3);
}

__global__ void __launch_bounds__(256)
pfn_stats_hist_kernel(const float* __restrict__ x, const int* __restrict__ idx,
                      int n, float* __restrict__ acc, int* __restrict__ hist) {
    const int tid = blockIdx.x * blockDim.x + threadIdx.x;
    const int stride = gridDim.x * blockDim.x;
    const int npairs = n >> 1;

    float s[27];
#pragma unroll
    for (int k = 0; k < 27; ++k) s[k] = 0.f;

    for (int q = tid; q < npairs; q += stride) {
        const float4* base4 = (const float4*)(x + (size_t)q * 12);
        const float4 a = base4[0];
        const float4 b4 = base4[1];
        const float4 c4 = base4[2];
        const float p0[6] = {a.x, a.y, a.z, a.w, b4.x, b4.y};
        const float p1[6] = {b4.z, b4.w, c4.x, c4.y, c4.z, c4.w};
#pragma unroll
        for (int j = 0; j < 6; ++j) s[j] += p0[j] + p1[j];
        int k = 6;
#pragma unroll
        for (int i = 0; i < 6; ++i)
#pragma unroll
            for (int j = i; j < 6; ++j) {
                s[k] += p0[i] * p0[j] + p1[i] * p1[j];
                ++k;
            }
    }
    if ((n & 1) && tid == 0) {
        const float* p = x + (size_t)(n - 1) * 6;
        float v[6];
#pragma unroll
        for (int j = 0; j < 6; ++j) v[j] = p[j];
#pragma unroll
        for (int j = 0; j < 6; ++j) s[j] += v[j];
        int k = 6;
#pragma unroll
        for (int i = 0; i < 6; ++i)
#pragma unroll
            for (int j = i; j < 6; ++j) { s[k] += v[i] * v[j]; ++k; }
    }

    // sub-bucket histogram: 2 points per int4, fire-and-forget atomics on 64KB
    for (int q = tid; q < npairs; q += stride) {
        const int4 ij2 = ((const int4*)idx)[q];
        atomicAdd(&hist[sub_bucket(ij2.x * N_PY + ij2.y)], 1);
        atomicAdd(&hist[sub_bucket(ij2.z * N_PY + ij2.w)], 1);
    }
    if ((n & 1) && tid == 0) {
        const int2 ij = ((const int2*)idx)[n - 1];
        atomicAdd(&hist[sub_bucket(ij.x * N_PY + ij.y)], 1);
    }

#pragma unroll
    for (int off = 32; off > 0; off >>= 1)
#pragma unroll
        for (int k = 0; k < 27; ++k) s[k] += __shfl_down(s[k], off, 64);

    __shared__ float lds[4][27];
    const int wid = threadIdx.x >> 6;
    const int lane = threadIdx.x & 63;
    if (lane == 0)
#pragma unroll
        for (int k = 0; k < 27; ++k) lds[wid][k] = s[k];
    __syncthreads();

    if (threadIdx.x < 27) {
        const int k = threadIdx.x;
        const float v = lds[0][k] + lds[1][k] + lds[2][k] + lds[3][k];
        atomicAdd(&acc[k], v);
    }
}

// single block, 1024 threads: exclusive scan of hist[16384] -> S[], cursor[],
// plus BN-param fold on threads 0..63.
__global__ void __launch_bounds__(1024)
pfn_scan_finalize_kernel(const int* __restrict__ hist,
                         int* __restrict__ S, int* __restrict__ cursor, int n,
                         const float* __restrict__ acc,
                         const float* __restrict__ W,
                         const float* __restrict__ b,
                         const float* __restrict__ gamma,
                         const float* __restrict__ beta,
                         float* __restrict__ Wp, float* __restrict__ bp) {
    const int tid = threadIdx.x;   // 1024 threads x 16 entries = 16384
    int v[16];
    const int4* h4 = (const int4*)(hist + tid * 16);
#pragma unroll
    for (int g = 0; g < 4; ++g) {
        const int4 q = h4[g];
        v[g * 4 + 0] = q.x; v[g * 4 + 1] = q.y;
        v[g * 4 + 2] = q.z; v[g * 4 + 3] = q.w;
    }
    int pre[16];
    int tot = 0;
#pragma unroll
    for (int k = 0; k < 16; ++k) { pre[k] = tot; tot += v[k]; }

    __shared__ int sc[1024];
    sc[tid] = tot;
    __syncthreads();
#pragma unroll
    for (int off = 1; off < 1024; off <<= 1) {
        const int add = (tid >= off) ? sc[tid - off] : 0;
        __syncthreads();
        sc[tid] += add;
        __syncthreads();
    }
    const int excl = sc[tid] - tot;
#pragma unroll
    for (int k = 0; k < 16; ++k) {
        const int val = excl + pre[k];
        S[tid * 16 + k] = val;
        cursor[tid * 16 + k] = val;
    }
    if (tid == 1023) S[N_SB] = n;

    // ---- BN-fold ----
    if (tid < 64) {
        const int f = tid;
        double inv_n = 1.0 / (double)n;
        double mx[6];
#pragma unroll
        for (int j = 0; j < 6; ++j) mx[j] = (double)acc[j] * inv_n;
        double C[6][6];
        {
            int k = 0;
            for (int i = 0; i < 6; ++i)
                for (int j = i; j < 6; ++j) {
                    double e = (double)acc[6 + k] * inv_n - mx[i] * mx[j];
                    C[i][j] = e; C[j][i] = e; ++k;
                }
        }
        double w[6];
#pragma unroll
        for (int j = 0; j < 6; ++j) w[j] = (double)W[f * 6 + j];
        double mean_h = (double)b[f];
#pragma unroll
        for (int j = 0; j < 6; ++j) mean_h += w[j] * mx[j];
        double var_h = 0.0;
        for (int i = 0; i < 6; ++i) {
            double t = 0.0;
            for (int j = 0; j < 6; ++j) t += C[i][j] * w[j];
            var_h += w[i] * t;
        }
        double sgn = (double)gamma[f] / sqrt(var_h + BN_EPS);
#pragma unroll
        for (int j = 0; j < 6; ++j) Wp[f * 6 + j] = (float)(w[j] * sgn);
        bp[f] = (float)(((double)b[f] - mean_h) * sgn + (double)beta[f]);
    }
}

// bin points: 2 points per thread (independent atomic+store chains for MLP),
// 32B-aligned record {x0..x5, cell, 0} into sub-bucket region
__global__ void __launch_bounds__(256)
pfn_bin_kernel(const float* __restrict__ x, const int* __restrict__ idx,
               int* __restrict__ cursor, float* __restrict__ rec, int n) {
    const int t = blockIdx.x * blockDim.x + threadIdx.x;
    const int pA = t * 2;
    if (pA >= n) return;
    const bool hasB = (pA + 1) < n;

    const int2 ijA = ((const int2*)idx)[pA];
    const int cellA = ijA.x * N_PY + ijA.y;
    int cellB = 0;
    if (hasB) {
        const int2 ijB = ((const int2*)idx)[pA + 1];
        cellB = ijB.x * N_PY + ijB.y;
    }

    // load both x rows first (independent, in flight together)
    const float2* xa = (const float2*)(x + (size_t)pA * 6);
    const float2 a0 = xa[0], a1 = xa[1], a2 = xa[2];
    float2 b0, b1, b2;
    if (hasB) {
        const float2* xb = (const float2*)(x + (size_t)(pA + 1) * 6);
        b0 = xb[0]; b1 = xb[1]; b2 = xb[2];
    }

    // two independent atomics in flight
    const int posA = atomicAdd(&cursor[sub_bucket(cellA)], 1);
    int posB = 0;
    if (hasB) posB = atomicAdd(&cursor[sub_bucket(cellB)], 1);

    float4* dA = (float4*)(rec + (size_t)posA * 8);
    dA[0] = float4{a0.x, a0.y, a1.x, a1.y};
    dA[1] = float4{a2.x, a2.y, __int_as_float(cellA), 0.f};
    if (hasB) {
        float4* dB = (float4*)(rec + (size_t)posB * 8);
        dB[0] = float4{b0.x, b0.y, b1.x, b1.y};
        dB[1] = float4{b2.x, b2.y, __int_as_float(cellB), 0.f};
    }
}

// one block per 64-cell bucket: accumulate into 16KB LDS tile, coalesced flush.
// wave w exclusively consumes sub-bucket (bucket*4+w) -> no races, no atomics.
// Inner loop unrolled by 4: 8 independent float4 loads in flight per chunk.
__global__ void __launch_bounds__(256)
pfn_tile_kernel(const float* __restrict__ rec, const int* __restrict__ S,
                const float* __restrict__ Wp, const float* __restrict__ bp,
                float* __restrict__ out) {
    __shared__ float tile[64 * OUT_F];   // 16 KB
    const int tid = threadIdx.x;
    const int lane = tid & 63;
    const int wid = tid >> 6;
    const int bucket = blockIdx.x;

    float4* t4 = (float4*)tile;
#pragma unroll
    for (int i = 0; i < 4; ++i)
        t4[tid + 256 * i] = float4{0.f, 0.f, 0.f, 0.f};

    const float w0 = Wp[lane * 6 + 0];
    const float w1 = Wp[lane * 6 + 1];
    const float w2 = Wp[lane * 6 + 2];
    const float w3 = Wp[lane * 6 + 3];
    const float w4 = Wp[lane * 6 + 4];
    const float w5 = Wp[lane * 6 + 5];
    const float bb = bp[lane];

    __syncthreads();

    const int sb = (bucket << 2) | wid;
    int r = S[sb];
    const int r1 = S[sb + 1];

    // main: 4 points per chunk, 8 loads issued before any use
    for (; r + 4 <= r1; r += 4) {
        const float4* q0 = (const float4*)(rec + (size_t)(r + 0) * 8);
        const float4* q1 = (const float4*)(rec + (size_t)(r + 1) * 8);
        const float4* q2 = (const float4*)(rec + (size_t)(r + 2) * 8);
        const float4* q3 = (const float4*)(rec + (size_t)(r + 3) * 8);
        const float4 a0 = q0[0], a1 = q0[1];
        const float4 b0 = q1[0], b1 = q1[1];
        const float4 c0 = q2[0], c1 = q2[1];
        const float4 d0 = q3[0], d1 = q3[1];

        float v;
        v = bb;
        v = fmaf(w0, a0.x, v); v = fmaf(w1, a0.y, v); v = fmaf(w2, a0.z, v);
        v = fmaf(w3, a0.w, v); v = fmaf(w4, a1.x, v); v = fmaf(w5, a1.y, v);
        tile[((__float_as_int(a1.z) & 63) << 6) | lane] += fmaxf(v, 0.f);

        v = bb;
        v = fmaf(w0, b0.x, v); v = fmaf(w1, b0.y, v); v = fmaf(w2, b0.z, v);
        v = fmaf(w3, b0.w, v); v = fmaf(w4, b1.x, v); v = fmaf(w5, b1.y, v);
        tile[((__float_as_int(b1.z) & 63) << 6) | lane] += fmaxf(v, 0.f);

        v = bb;
        v = fmaf(w0, c0.x, v); v = fmaf(w1, c0.y, v); v = fmaf(w2, c0.z, v);
        v = fmaf(w3, c0.w, v); v = fmaf(w4, c1.x, v); v = fmaf(w5, c1.y, v);
        tile[((__float_as_int(c1.z) & 63) << 6) | lane] += fmaxf(v, 0.f);

        v = bb;
        v = fmaf(w0, d0.x, v); v = fmaf(w1, d0.y, v); v = fmaf(w2, d0.z, v);
        v = fmaf(w3, d0.w, v); v = fmaf(w4, d1.x, v); v = fmaf(w5, d1.y, v);
        tile[((__float_as_int(d1.z) & 63) << 6) | lane] += fmaxf(v, 0.f);
    }
    // tail (<=3)
    for (; r < r1; ++r) {
        const float4* q = (const float4*)(rec + (size_t)r * 8);
        const float4 A0 = q[0], A1 = q[1];
        float v = bb;
        v = fmaf(w0, A0.x, v); v = fmaf(w1, A0.y, v); v = fmaf(w2, A0.z, v);
        v = fmaf(w3, A0.w, v); v = fmaf(w4, A1.x, v); v = fmaf(w5, A1.y, v);
        tile[((__float_as_int(A1.z) & 63) << 6) | lane] += fmaxf(v, 0.f);
    }
    __syncthreads();

    float4* o4 = (float4*)(out + (size_t)bucket * (64 * OUT_F));
#pragma unroll
    for (int i = 0; i < 4; ++i)
        o4[tid + 256 * i] = t4[tid + 256 * i];
}

// ---- fallback (linked-list path, small ws) ----
__global__ void __launch_bounds__(256)
pfn_build_kernel(const int* __restrict__ idx, int n,
                 int* __restrict__ head, int* __restrict__ nxt) {
    const int p = blockIdx.x * blockDim.x + threadIdx.x;
    if (p >= n) return;
    const int2 ij = ((const int2*)idx)[p];
    const int cell = ij.x * N_PY + ij.y;
    nxt[p] = atomicExch(&head[cell], p);
}

__global__ void pfn_finalize_kernel(const float* __restrict__ acc,
                                    const float* __restrict__ W,
                                    const float* __restrict__ b,
                                    const float* __restrict__ gamma,
                                    const float* __restrict__ beta,
                                    int n,
                                    float* __restrict__ Wp,
                                    float* __restrict__ bp) {
    int f = threadIdx.x;
    double inv_n = 1.0 / (double)n;
    double mx[6];
#pragma unroll
    for (int j = 0; j < 6; ++j) mx[j] = (double)acc[j] * inv_n;
    double C[6][6];
    {
        int k = 0;
        for (int i = 0; i < 6; ++i)
            for (int j = i; j < 6; ++j) {
                double e = (double)acc[6 + k] * inv_n - mx[i] * mx[j];
                C[i][j] = e; C[j][i] = e; ++k;
            }
    }
    double w[6];
#pragma unroll
    for (int j = 0; j < 6; ++j) w[j] = (double)W[f * 6 + j];
    double mean_h = (double)b[f];
#pragma unroll
    for (int j = 0; j < 6; ++j) mean_h += w[j] * mx[j];
    double var_h = 0.0;
    for (int i = 0; i < 6; ++i) {
        double t = 0.0;
        for (int j = 0; j < 6; ++j) t += C[i][j] * w[j];
        var_h += w[i] * t;
    }
    double s = (double)gamma[f] / sqrt(var_h + BN_EPS);
#pragma unroll
    for (int j = 0; j < 6; ++j) Wp[f * 6 + j] = (float)(w[j] * s);
    bp[f] = (float)(((double)b[f] - mean_h) * s + (double)beta[f]);
}

__global__ void __launch_bounds__(256)
pfn_output_kernel(const float* __restrict__ x,
                  const int* __restrict__ head,
                  const int* __restrict__ nxt,
                  const float* __restrict__ Wp,
                  const float* __restrict__ bp,
                  float* __restrict__ out) {
    const int lane = threadIdx.x & 63;
    const int cell = __builtin_amdgcn_readfirstlane(
        (int)((blockIdx.x * blockDim.x + threadIdx.x) >> 6));

    const float w0 = Wp[lane * 6 + 0];
    const float w1 = Wp[lane * 6 + 1];
    const float w2 = Wp[lane * 6 + 2];
    const float w3 = Wp[lane * 6 + 3];
    const float w4 = Wp[lane * 6 + 4];
    const float w5 = Wp[lane * 6 + 5];
    const float bb = bp[lane];

    float s = 0.f;
    int p = head[cell];
    while (p >= 0) {
        const float* xp = x + (size_t)p * 6;
        const int pn = nxt[p];
        float v = bb;
        v = fmaf(w0, xp[0], v);
        v = fmaf(w1, xp[1], v);
        v = fmaf(w2, xp[2], v);
        v = fmaf(w3, xp[3], v);
        v = fmaf(w4, xp[4], v);
        v = fmaf(w5, xp[5], v);
        s += fmaxf(v, 0.0f);
        p = pn;
    }
    out[(size_t)cell * OUT_F + lane] = s;
}

extern "C" void kernel_launch(void* const* d_in, const int* in_sizes, int n_in,
                              void* d_out, int out_size, void* d_ws, size_t ws_size,
                              hipStream_t stream) {
    const float* x     = (const float*)d_in[0];
    const int*   idx   = (const int*)d_in[1];
    const float* W     = (const float*)d_in[2];
    const float* b     = (const float*)d_in[3];
    const float* gamma = (const float*)d_in[4];
    const float* beta  = (const float*)d_in[5];
    float* out = (float*)d_out;

    const int n = in_sizes[0] / IN_F;

    float* acc = (float*)d_ws;
    float* Wp  = (float*)((char*)d_ws + 512);
    float* bp  = Wp + OUT_F * IN_F;

    int*   hist   = (int*)((char*)d_ws + 4096);     // 16384 ints
    int*   S      = (int*)((char*)d_ws + 69632);    // 16385 ints
    int*   cursor = (int*)((char*)d_ws + 135680);   // 16384 ints
    float* rec    = (float*)((char*)d_ws + 201216); // n * 8 floats, 32B recs

    const size_t need = 201216 + (size_t)n * 32;

    if (ws_size >= need) {
        // zero acc + hist in one memset (S/cursor fully written by scan kernel)
        hipMemsetAsync(d_ws, 0, 69632, stream);
        pfn_stats_hist_kernel<<<512, 256, 0, stream>>>(x, idx, n, acc, hist);
        pfn_scan_finalize_kernel<<<1, 1024, 0, stream>>>(
            hist, S, cursor, n, acc, W, b, gamma, beta, Wp, bp);
        pfn_bin_kernel<<<((n + 1) / 2 + 255) / 256, 256, 0, stream>>>(
            x, idx, cursor, rec, n);
        pfn_tile_kernel<<<N_BUCKETS, 256, 0, stream>>>(rec, S, Wp, bp, out);
    } else {
        // linked-list fallback
        int* head = (int*)((char*)d_ws + 4096);
        int* nxt  = head + N_CELLS;
        hipMemsetAsync(d_ws, 0, 512, stream);
        pfn_stats_hist_kernel<<<512, 256, 0, stream>>>(x, idx, n, acc, head);
        hipMemsetAsync(head, 0xFF, (size_t)N_CELLS * sizeof(int), stream);
        pfn_finalize_kernel<<<1, 64, 0, stream>>>(acc, W, b, gamma, beta, n, Wp, bp);
        pfn_build_kernel<<<(n + 255) / 256, 256, 0, stream>>>(idx, n, head, nxt);
        pfn_output_kernel<<<N_CELLS / 4, 256, 0, stream>>>(x, head, nxt, Wp, bp, out);
    }
}